// Round 5
// baseline (181.679 us; speedup 1.0000x reference)
//
#include <hip/hip_runtime.h>
#include <hip/hip_bf16.h>
#include <math.h>

#define N 8192
#define D 128
#define MARGIN 4e-5f
#define FLAGBIT 0x80000000
#define IDXMASK 0x1FFF

typedef __attribute__((ext_vector_type(8))) short short8;
typedef __attribute__((ext_vector_type(4))) float f32x4;
typedef unsigned long long u64;

__device__ __forceinline__ unsigned int ordered_u32(float f) {
    unsigned int b = __float_as_uint(f);
    return (b & 0x80000000u) ? ~b : (b | 0x80000000u);
}
__device__ __forceinline__ float ordered_inv(unsigned int u) {
    unsigned int b = (u & 0x80000000u) ? (u & 0x7FFFFFFFu) : ~u;
    return __uint_as_float(b);
}

// ---------------- prep: normalize, split to bf16 hi/lo, norms, init keys/counter
__global__ __launch_bounds__(256) void prep_kernel(const float* __restrict__ e,
                                                   __hip_bfloat16* __restrict__ hi,
                                                   __hip_bfloat16* __restrict__ lo,
                                                   float* __restrict__ nrm,
                                                   int* __restrict__ counter,
                                                   u64* __restrict__ pos_key,
                                                   u64* __restrict__ neg_key) {
    if (blockIdx.x == 0 && threadIdx.x == 0) *counter = 0;
    int row  = blockIdx.x * 4 + (threadIdx.x >> 6);
    int lane = threadIdx.x & 63;
    if (lane == 0) { pos_key[row] = ~0ull; neg_key[row] = ~0ull; }
    float2 v = ((const float2*)(e + (size_t)row * D))[lane];
    float s = v.x * v.x + v.y * v.y;
    #pragma unroll
    for (int m = 1; m < 64; m <<= 1) s += __shfl_xor(s, m, 64);
    float nr = sqrtf(s);
    if (lane == 0) nrm[row] = nr;
    float rn = 1.0f / fmaxf(nr, 1e-8f);
    float e0 = v.x * rn, e1 = v.y * rn;
    __hip_bfloat16 h0 = __float2bfloat16(e0);
    __hip_bfloat16 h1 = __float2bfloat16(e1);
    __hip_bfloat16 l0 = __float2bfloat16(e0 - __bfloat162float(h0));
    __hip_bfloat16 l1 = __float2bfloat16(e1 - __bfloat162float(h1));
    ushort2 hh, ll;
    hh.x = *(unsigned short*)&h0; hh.y = *(unsigned short*)&h1;
    ll.x = *(unsigned short*)&l0; ll.y = *(unsigned short*)&l1;
    ((ushort2*)hi)[row * 64 + lane] = hh;
    ((ushort2*)lo)[row * 64 + lane] = ll;
}

// ---------------- mine: A LDS-resident, B from L2 with 2-deep register pipeline
__global__ __launch_bounds__(256, 2) void mine_kernel(
    const __hip_bfloat16* __restrict__ hi, const __hip_bfloat16* __restrict__ lo,
    const int* __restrict__ labels, int4* __restrict__ partials) {

    __shared__ short Ahi[128 * 128];
    __shared__ short Alo[128 * 128];
    __shared__ int   lab_sh[1024];

    const int tid = threadIdx.x;
    const int l = tid & 63;
    const int w = tid >> 6;
    const int ihalf = w >> 1, jhalf = w & 1;
    const int i0 = blockIdx.x * 128;
    const int j0base = blockIdx.y * 1024;
    const int lq = l >> 4;
    const int ln = l & 15;

    // ---- stage A (hi+lo, full K=128), swizzled: chunk c stored at slot c^(r&7)
    {
        const int arr = tid >> 7;
        const int r = tid & 127;
        const __hip_bfloat16* src = (arr ? lo : hi) + (size_t)(i0 + r) * D;
        short* dst = (arr ? Alo : Ahi) + r * 128;
        #pragma unroll
        for (int c = 0; c < 16; ++c) {
            short8 vv = *(const short8*)(src + c * 8);
            *(short8*)(dst + ((c ^ (r & 7)) * 8)) = vv;
        }
    }
    {
        int4 lv = ((const int4*)(labels + j0base))[tid];
        ((int4*)lab_sh)[tid] = lv;
    }

    const short* __restrict__ hs = (const short*)hi;
    const short* __restrict__ ls = (const short*)lo;

    // ---- B register double-buffer; issue round 0 before the barrier
    short8 bH[2][4], bL[2][4];
    // fixed per-lane address component (shorts): (jhalf*64 + nt*16 + ln)*D + lq*8
    const size_t lanoff = (size_t)(j0base + jhalf * 64 + ln) * D + lq * 8;

#define ISSUE_B(rr, buf) do {                                                   \
        const int jt_ = (rr) >> 2, kc_ = (rr) & 3;                              \
        const size_t base_ = lanoff + (size_t)jt_ * 128 * D + kc_ * 32;         \
        _Pragma("unroll")                                                       \
        for (int nt_ = 0; nt_ < 4; ++nt_) {                                     \
            bH[buf][nt_] = *(const short8*)(hs + base_ + (size_t)nt_ * 16 * D); \
            bL[buf][nt_] = *(const short8*)(ls + base_ + (size_t)nt_ * 16 * D); \
        }                                                                       \
    } while (0)

    ISSUE_B(0, 0);
    __syncthreads();   // the only barrier

    // per-lane anchor labels / index bases
    int li[16];
    int ibase[4];
    #pragma unroll
    for (int mt = 0; mt < 4; ++mt) ibase[mt] = i0 + ihalf * 64 + mt * 16 + lq * 4;
    #pragma unroll
    for (int s = 0; s < 16; ++s) li[s] = labels[ibase[s >> 2] + (s & 3)];

    float posv[16], negv[16];
    int   posi[16], negi[16];
    #pragma unroll
    for (int s = 0; s < 16; ++s) {
        posv[s] = -INFINITY; posi[s] = 0;
        negv[s] =  INFINITY; negi[s] = 0;
    }

    f32x4 acc[4][4];
    #pragma unroll
    for (int mt = 0; mt < 4; ++mt)
        #pragma unroll
        for (int nt = 0; nt < 4; ++nt) acc[mt][nt] = (f32x4){0.f, 0.f, 0.f, 0.f};

    // ---- 32 pipelined rounds: r = jt*4 + kc
    #pragma unroll 2
    for (int r = 0; r < 32; ++r) {
        const int cur = r & 1;
        if (r < 31) ISSUE_B(r + 1, cur ^ 1);
        const int kc = r & 3;

        #pragma unroll
        for (int mt = 0; mt < 4; ++mt) {
            int row = ihalf * 64 + mt * 16 + ln;
            int slot = (kc * 4 + lq) ^ (ln & 7);
            short8 ah = *(short8*)(Ahi + row * 128 + slot * 8);
            short8 al = *(short8*)(Alo + row * 128 + slot * 8);
            #pragma unroll
            for (int nt = 0; nt < 4; ++nt) {
                acc[mt][nt] = __builtin_amdgcn_mfma_f32_16x16x32_bf16(ah, bH[cur][nt], acc[mt][nt], 0, 0, 0);
                acc[mt][nt] = __builtin_amdgcn_mfma_f32_16x16x32_bf16(ah, bL[cur][nt], acc[mt][nt], 0, 0, 0);
                acc[mt][nt] = __builtin_amdgcn_mfma_f32_16x16x32_bf16(al, bH[cur][nt], acc[mt][nt], 0, 0, 0);
            }
        }

        if (kc == 3) {
            // ---- epilogue for jt = r>>2
            const int j0 = j0base + (r >> 2) * 128;
            const int jrow0 = j0 + jhalf * 64 + ln;
            int jv[4], lj[4];
            #pragma unroll
            for (int nt = 0; nt < 4; ++nt) {
                jv[nt] = jrow0 + nt * 16;
                lj[nt] = lab_sh[jv[nt] - j0base];
            }
            #pragma unroll
            for (int nt = 0; nt < 4; ++nt) {
                #pragma unroll
                for (int mt = 0; mt < 4; ++mt) {
                    #pragma unroll
                    for (int rr = 0; rr < 4; ++rr) {
                        const int s = mt * 4 + rr;
                        float dd = 1.0f - acc[mt][nt][rr];
                        bool same = (lj[nt] == li[s]);
                        bool self = (jv[nt] == ibase[mt] + rr);
                        if (same) {
                            if (!self) {
                                bool nr = fabsf(dd - posv[s]) < MARGIN;
                                if (dd > posv[s]) { posv[s] = dd; posi[s] = jv[nt] | (nr ? FLAGBIT : 0); }
                                else if (nr) posi[s] |= FLAGBIT;
                            }
                        } else {
                            bool nr = fabsf(dd - negv[s]) < MARGIN;
                            if (dd < negv[s]) { negv[s] = dd; negi[s] = jv[nt] | (nr ? FLAGBIT : 0); }
                            else if (nr) negi[s] |= FLAGBIT;
                        }
                    }
                }
            }
            #pragma unroll
            for (int mt = 0; mt < 4; ++mt)
                #pragma unroll
                for (int nt = 0; nt < 4; ++nt) acc[mt][nt] = (f32x4){0.f, 0.f, 0.f, 0.f};
        }
    }
#undef ISSUE_B

    // ---- cross-lane butterfly + partial write
    #pragma unroll
    for (int s = 0; s < 16; ++s) {
        float pv = posv[s]; int pif = posi[s];
        float nv = negv[s]; int nif = negi[s];
        #pragma unroll
        for (int off = 1; off < 16; off <<= 1) {
            float opv = __shfl_xor(pv, off, 64); int opif = __shfl_xor(pif, off, 64);
            float onv = __shfl_xor(nv, off, 64); int onif = __shfl_xor(nif, off, 64);
            bool pnr = fabsf(opv - pv) < MARGIN;
            bool nnr = fabsf(onv - nv) < MARGIN;
            if (opv > pv) { pv = opv; pif = opif; }
            if (pnr) pif |= FLAGBIT;
            if (onv < nv) { nv = onv; nif = onif; }
            if (nnr) nif |= FLAGBIT;
        }
        if (ln == s) {
            int ii = ibase[s >> 2] + (s & 3);
            partials[ii * 16 + blockIdx.y * 2 + jhalf] =
                make_int4(__float_as_int(pv), pif, __float_as_int(nv), nif);
        }
    }
}

// ---------------- combine: fold 16 partials/row (4 lanes/row), outputs + flag list
__global__ __launch_bounds__(256) void combine_kernel(
    const int4* __restrict__ partials, float* __restrict__ out,
    int* __restrict__ list, int* __restrict__ counter) {
    int tid = threadIdx.x;
    int a = blockIdx.x * 64 + (tid >> 2);
    int q = tid & 3;
    float pv = -INFINITY; int pif = 0;
    float nv =  INFINITY; int nif = 0;
    #pragma unroll
    for (int s = 0; s < 4; ++s) {
        int4 p = partials[a * 16 + q * 4 + s];
        float dv = __int_as_float(p.x);
        bool nr = fabsf(dv - pv) < MARGIN;
        if (dv > pv) { pv = dv; pif = p.y; }
        if (nr) pif |= FLAGBIT;
        float ev = __int_as_float(p.z);
        bool nr2 = fabsf(ev - nv) < MARGIN;
        if (ev < nv) { nv = ev; nif = p.w; }
        if (nr2) nif |= FLAGBIT;
    }
    #pragma unroll
    for (int off = 1; off < 4; off <<= 1) {
        float opv = __shfl_xor(pv, off, 64); int opif = __shfl_xor(pif, off, 64);
        float onv = __shfl_xor(nv, off, 64); int onif = __shfl_xor(nif, off, 64);
        bool pnr = fabsf(opv - pv) < MARGIN;
        bool nnr = fabsf(onv - nv) < MARGIN;
        int opidx = opif & IDXMASK, pidx = pif & IDXMASK;
        if (opv > pv || (opv == pv && opidx < pidx)) { pv = opv; pif = opif; }
        if (pnr) pif |= FLAGBIT;
        int onidx = onif & IDXMASK, nidx = nif & IDXMASK;
        if (onv < nv || (onv == nv && onidx < nidx)) { nv = onv; nif = onif; }
        if (nnr) nif |= FLAGBIT;
    }
    if (q == 0) {
        out[a * 3 + 0] = (float)a;
        out[a * 3 + 1] = (float)(pif & IDXMASK);
        out[a * 3 + 2] = (float)(nif & IDXMASK);
        out[3 * N + a] = pv;
        out[4 * N + a] = nv;
        if ((pif | nif) & FLAGBIT) {
            int k = atomicAdd(counter, 1);
            list[k] = a;
        }
    }
}

// ---------------- cleanup pass 1: exact fp32, one j per thread, u64 atomicMin merge
__global__ __launch_bounds__(256) void cleanup1_kernel(
    const float* __restrict__ e, const int* __restrict__ labels,
    const float* __restrict__ nrm, const int* __restrict__ list,
    const int* __restrict__ counter,
    u64* __restrict__ pos_key, u64* __restrict__ neg_key) {
    __shared__ float enr[128];
    __shared__ u64 redp[4], redn[4];
    const int tid = threadIdx.x;
    const int lane = tid & 63, w = tid >> 6;
    const int cnt = *counter;
    const int j = blockIdx.y * 256 + tid;

    for (int slot = blockIdx.x; slot < cnt; slot += gridDim.x) {
        __syncthreads();
        const int row = list[slot];
        if (tid < 128) enr[tid] = e[(size_t)row * D + tid] / fmaxf(nrm[row], 1e-8f);
        __syncthreads();
        const int lr = labels[row];

        const float4* ej = (const float4*)(e + (size_t)j * D);
        float s0 = 0.f, s1 = 0.f, s2 = 0.f, s3 = 0.f;
        #pragma unroll
        for (int c = 0; c < 32; c += 4) {
            float4 v0 = ej[c], v1 = ej[c + 1], v2 = ej[c + 2], v3 = ej[c + 3];
            s0 = fmaf(v0.x, enr[4*c   ], fmaf(v0.y, enr[4*c+ 1], fmaf(v0.z, enr[4*c+ 2], fmaf(v0.w, enr[4*c+ 3], s0))));
            s1 = fmaf(v1.x, enr[4*c+ 4], fmaf(v1.y, enr[4*c+ 5], fmaf(v1.z, enr[4*c+ 6], fmaf(v1.w, enr[4*c+ 7], s1))));
            s2 = fmaf(v2.x, enr[4*c+ 8], fmaf(v2.y, enr[4*c+ 9], fmaf(v2.z, enr[4*c+10], fmaf(v2.w, enr[4*c+11], s2))));
            s3 = fmaf(v3.x, enr[4*c+12], fmaf(v3.y, enr[4*c+13], fmaf(v3.z, enr[4*c+14], fmaf(v3.w, enr[4*c+15], s3))));
        }
        float dd = 1.0f - ((s0 + s1) + (s2 + s3)) / fmaxf(nrm[j], 1e-8f);

        u64 pk = ~0ull, nk = ~0ull;
        if (j != row) {
            unsigned int u = ordered_u32(dd);
            if (labels[j] == lr) pk = ((u64)(~u) << 32) | (unsigned int)j;
            else                 nk = ((u64)( u) << 32) | (unsigned int)j;
        }
        #pragma unroll
        for (int off = 1; off < 64; off <<= 1) {
            u64 op = __shfl_xor(pk, off, 64); if (op < pk) pk = op;
            u64 on = __shfl_xor(nk, off, 64); if (on < nk) nk = on;
        }
        if (lane == 0) { redp[w] = pk; redn[w] = nk; }
        __syncthreads();
        if (tid == 0) {
            #pragma unroll
            for (int q = 1; q < 4; ++q) {
                if (redp[q] < pk) pk = redp[q];
                if (redn[q] < nk) nk = redn[q];
            }
            if (pk != ~0ull) atomicMin(&pos_key[row], pk);
            if (nk != ~0ull) atomicMin(&neg_key[row], nk);
        }
    }
}

// ---------------- cleanup pass 2: decode keys, overwrite flagged rows ----------
__global__ __launch_bounds__(256) void cleanup2_kernel(
    const u64* __restrict__ pos_key, const u64* __restrict__ neg_key,
    const int* __restrict__ list, const int* __restrict__ counter,
    float* __restrict__ out) {
    int idx = blockIdx.x * 256 + threadIdx.x;
    int cnt = *counter;
    if (idx >= cnt) return;
    int row = list[idx];
    u64 pk = pos_key[row], nk = neg_key[row];
    if (pk != ~0ull) {
        unsigned int u = ~(unsigned int)(pk >> 32);
        out[row * 3 + 1] = (float)(unsigned int)(pk & 0xFFFFFFFFu);
        out[3 * N + row] = ordered_inv(u);
    }
    if (nk != ~0ull) {
        unsigned int u = (unsigned int)(nk >> 32);
        out[row * 3 + 2] = (float)(unsigned int)(nk & 0xFFFFFFFFu);
        out[4 * N + row] = ordered_inv(u);
    }
}

extern "C" void kernel_launch(void* const* d_in, const int* in_sizes, int n_in,
                              void* d_out, int out_size, void* d_ws, size_t ws_size,
                              hipStream_t stream) {
    const float* e      = (const float*)d_in[0];
    const int*   labels = (const int*)d_in[1];
    float* out = (float*)d_out;

    char* wsb = (char*)d_ws;
    __hip_bfloat16* hi = (__hip_bfloat16*)wsb;                          // 2 MB
    __hip_bfloat16* lo = hi + (size_t)N * D;                            // 2 MB
    float* nrm   = (float*)(wsb + 4u * 1024 * 1024);                    // 32 KB
    int4*  parts = (int4*)(wsb + 4u * 1024 * 1024 + 65536);             // 2 MB
    int*   list  = (int*)(wsb + 7u * 1024 * 1024);                      // 32 KB
    int*   cnt   = (int*)(wsb + 7u * 1024 * 1024 + 65536);              // 4 B
    u64*   pkey  = (u64*)(wsb + 7u * 1024 * 1024 + 131072);             // 64 KB
    u64*   nkey  = (u64*)(wsb + 7u * 1024 * 1024 + 196608);             // 64 KB

    prep_kernel<<<N / 4, 256, 0, stream>>>(e, hi, lo, nrm, cnt, pkey, nkey);
    mine_kernel<<<dim3(N / 128, 8), 256, 0, stream>>>(hi, lo, labels, parts);
    combine_kernel<<<N / 64, 256, 0, stream>>>(parts, out, list, cnt);
    cleanup1_kernel<<<dim3(256, 32), 256, 0, stream>>>(e, labels, nrm, list, cnt, pkey, nkey);
    cleanup2_kernel<<<N / 256, 256, 0, stream>>>(pkey, nkey, list, cnt, out);
}